// Round 7
// baseline (43.348 us; speedup 1.0000x reference)
//
#include <hip/hip_runtime.h>

// Problem geometry (fixed by the reference): u is (B=2, C=3, D=160, H=192, W=160) float32.
#define Dd 160
#define Hh 192
#define Ww 160
#define HW (Hh * Ww)                       // 30720
#define DHW ((size_t)Dd * HW)              // 4,915,200
#define NVOX_D 9830400.0                   // 2 * 160*192*160

// One block per CU: 960 threads = 15 waves, TH=24 rows x TD=10 planes.
// Halo factor (26/24)*(12/10) = 1.30x (was 1.50x with TH=8): 177 -> 153 MB fetch.
#define TH 24                               // h-rows per block (1 row per thread)
#define TD 10                               // d-planes per block (sliding window)
#define QROW (Ww / 4)                       // 40 float4-quads per row
#define TPB (QROW * TH)                     // 960 threads = 15 waves
#define NHT (Hh / TH)                       // 8
#define NDS (Dd / TD)                       // 16
#define GRID1 (2 * NHT * NDS)               // 256 blocks = exactly 1 per CU
#define NXCD 8
#define CHUNK (GRID1 / NXCD)                // 32 logical blocks per XCD
#define NWAVE (TPB / 64)                    // 15

__device__ __forceinline__ float4 ld4(const float* p) {
    return *reinterpret_cast<const float4*>(p);
}

// w-gradient for a quad given its left/right edge scalars (jnp.gradient semantics)
__device__ __forceinline__ float4 wgrad(float4 cc, float lft, float rgt, int w0) {
    float4 g;
    g.x = (w0 == 0)      ? (cc.y - cc.x) : 0.5f * (cc.y - lft);
    g.y = 0.5f * (cc.z - cc.x);
    g.z = 0.5f * (cc.w - cc.y);
    g.w = (w0 + 4 == Ww) ? (cc.w - cc.z) : 0.5f * (rgt - cc.z);
    return g;
}

// relu(-det(J)) for one voxel given the 9 raw (unscaled) finite-difference grads.
__device__ __forceinline__ float relu_negdet(
    float gd0, float gh0, float gw0,
    float gd1, float gh1, float gw1,
    float gd2, float gh2, float gw2)
{
    const float sx = 79.5f;   // (D-1)/2 -> channel 0
    const float sy = 95.5f;   // (H-1)/2 -> channel 1
    const float sz = 79.5f;   // (W-1)/2 -> channel 2
    float dxx = fmaf(sx, gd0, 1.0f);
    float dxy = sx * gh0;
    float dxz = sx * gw0;
    float dyx = sy * gd1;
    float dyy = fmaf(sy, gh1, 1.0f);
    float dyz = sy * gw1;
    float dzx = sz * gd2;
    float dzy = sz * gh2;
    float dzz = fmaf(sz, gw2, 1.0f);
    float det = dxx * (dyy * dzz - dyz * dzy)
              + dxy * (dyz * dzx - dyx * dzz)
              + dxz * (dyx * dzy - dyy * dzx);
    return fmaxf(-det, 0.0f);
}

// Register-sliding d-march, 1 block/CU, minimal-halo blocking.
//  - XCD-chunked bijective swizzle (256 = 8*32, ds fastest): ds-neighbor blocks
//    (who share the d-halo planes, the 0.2x component) sit on the same XCD L2.
//  - boustrophedon d-march: shared boundary planes are read by both neighbors
//    at the same phase of their lifetime -> temporally adjacent -> L2-absorbable.
__global__ __launch_bounds__(TPB) void jac_partial(const float* __restrict__ u,
                                                   float* __restrict__ part)
{
    const int lg  = (blockIdx.x % NXCD) * CHUNK + blockIdx.x / NXCD;
    const int ds  = lg % NDS;
    const int ht  = (lg / NDS) % NHT;
    const int b   = lg / (NDS * NHT);

    const int tid = threadIdx.x;
    const int wq  = tid % QROW;
    const int hh  = tid / QROW;
    const int h   = ht * TH + hh;
    const int w0  = wq * 4;

    // jnp.gradient edge handling via clamped indices (one-sided at h=0/H-1)
    const int hm = (h > 0)      ? h - 1 : 0;
    const int hp = (h < Hh - 1) ? h + 1 : Hh - 1;
    const float hinv = 1.0f / (float)(hp - hm);
    const int offm = (hm - h) * Ww;   // 0 or -Ww
    const int offp = (hp - h) * Ww;   // 0 or +Ww

    const int d0     = ds * TD;
    const int dir    = (ds & 1) ? -1 : 1;              // boustrophedon
    const int dstart = (dir > 0) ? d0 : d0 + TD - 1;

    // channel base pointers at (b, c, d=0, h, w0)
    const float* pcA = u + (size_t)(b * 3 + 0) * DHW + (size_t)h * Ww + w0;
    const float* pcB = pcA + DHW;
    const float* pcC = pcA + 2 * DHW;

    // sliding window: x0 = plane (dstart - dir) [behind], x1 = plane dstart
    float4 a0, a1, b0, b1, c0, c1;
    {
        int db = dstart - dir;
        db = (db < 0) ? 0 : ((db > Dd - 1) ? Dd - 1 : db);
        const size_t om = (size_t)db * HW;
        const size_t oc = (size_t)dstart * HW;
        a0 = ld4(pcA + om);  a1 = ld4(pcA + oc);
        b0 = ld4(pcB + om);  b1 = ld4(pcB + oc);
        c0 = ld4(pcC + om);  c1 = ld4(pcC + oc);
    }

    float acc = 0.0f;

    #pragma unroll 2
    for (int i = 0; i < TD; ++i) {
        const int d  = dstart + dir * i;
        int dn = d + dir;                               // incoming plane
        dn = (dn < 0) ? 0 : ((dn > Dd - 1) ? Dd - 1 : dn);
        // ascending: x2=d+1,x0=d-1 -> (x2-x0)*dinv ; descending: sign folds in.
        const float dinvs = (float)dir * ((d > 0 && d < Dd - 1) ? 0.5f : 1.0f);
        const size_t od  = (size_t)d  * HW;
        const size_t odn = (size_t)dn * HW;

        // issue incoming-plane center loads first (consumed last -> latency hidden)
        float4 a2 = ld4(pcA + odn);
        float4 b2 = ld4(pcB + odn);
        float4 c2 = ld4(pcC + odn);

        const float* pdA = pcA + od;
        const float* pdB = pcB + od;
        const float* pdC = pcC + od;

        // h-neighbor quads at plane d (L1/L2 hits: siblings loaded them as centers)
        float4 rAm = ld4(pdA + offm), rAp = ld4(pdA + offp);
        float4 rBm = ld4(pdB + offm), rBp = ld4(pdB + offp);
        float4 rCm = ld4(pdC + offm), rCp = ld4(pdC + offp);

        // w-edge scalars (cache hits)
        float lA = (w0 > 0) ? pdA[-1] : 0.0f;
        float lB = (w0 > 0) ? pdB[-1] : 0.0f;
        float lC = (w0 > 0) ? pdC[-1] : 0.0f;
        float rA = (w0 + 4 < Ww) ? pdA[4] : 0.0f;
        float rB = (w0 + 4 < Ww) ? pdB[4] : 0.0f;
        float rC = (w0 + 4 < Ww) ? pdC[4] : 0.0f;

        // gradients (raw, unscaled)
        float4 gwA = wgrad(a1, lA, rA, w0);
        float4 gwB = wgrad(b1, lB, rB, w0);
        float4 gwC = wgrad(c1, lC, rC, w0);

        float4 ghA = make_float4((rAp.x - rAm.x) * hinv, (rAp.y - rAm.y) * hinv,
                                 (rAp.z - rAm.z) * hinv, (rAp.w - rAm.w) * hinv);
        float4 ghB = make_float4((rBp.x - rBm.x) * hinv, (rBp.y - rBm.y) * hinv,
                                 (rBp.z - rBm.z) * hinv, (rBp.w - rBm.w) * hinv);
        float4 ghC = make_float4((rCp.x - rCm.x) * hinv, (rCp.y - rCm.y) * hinv,
                                 (rCp.z - rCm.z) * hinv, (rCp.w - rCm.w) * hinv);

        float4 gdA = make_float4((a2.x - a0.x) * dinvs, (a2.y - a0.y) * dinvs,
                                 (a2.z - a0.z) * dinvs, (a2.w - a0.w) * dinvs);
        float4 gdB = make_float4((b2.x - b0.x) * dinvs, (b2.y - b0.y) * dinvs,
                                 (b2.z - b0.z) * dinvs, (b2.w - b0.w) * dinvs);
        float4 gdC = make_float4((c2.x - c0.x) * dinvs, (c2.y - c0.y) * dinvs,
                                 (c2.z - c0.z) * dinvs, (c2.w - c0.w) * dinvs);

        acc += relu_negdet(gdA.x, ghA.x, gwA.x, gdB.x, ghB.x, gwB.x, gdC.x, ghC.x, gwC.x)
             + relu_negdet(gdA.y, ghA.y, gwA.y, gdB.y, ghB.y, gwB.y, gdC.y, ghC.y, gwC.y)
             + relu_negdet(gdA.z, ghA.z, gwA.z, gdB.z, ghB.z, gwB.z, gdC.z, ghC.z, gwC.z)
             + relu_negdet(gdA.w, ghA.w, gwA.w, gdB.w, ghB.w, gwB.w, gdC.w, ghC.w, gwC.w);

        // slide the window
        a0 = a1; a1 = a2;
        b0 = b1; b1 = b2;
        c0 = c1; c1 = c2;
    }

    // deterministic block reduction: wave64 shuffle tree, then 15-word LDS
    #pragma unroll
    for (int off = 32; off > 0; off >>= 1)
        acc += __shfl_down(acc, off, 64);
    __shared__ float sred[NWAVE];
    const int lane = tid & 63;
    const int wid  = tid >> 6;
    if (lane == 0) sred[wid] = acc;
    __syncthreads();
    if (tid == 0) {
        float s = 0.0f;
        #pragma unroll
        for (int i = 0; i < NWAVE; ++i) s += sred[i];
        part[lg] = s;
    }
}

// 256 partials -> mean. Exactly 1 load per thread, f64 fixed-tree reduce
// (deterministic; f64 kills the ~2e8-magnitude sum's rounding concern).
__global__ __launch_bounds__(GRID1) void jac_final(const float* __restrict__ part,
                                                   float* __restrict__ out)
{
    const int t = threadIdx.x;
    __shared__ double s[GRID1];
    s[t] = (double)part[t];
    __syncthreads();
    #pragma unroll
    for (int off = GRID1 / 2; off > 0; off >>= 1) {
        if (t < off) s[t] += s[t + off];
        __syncthreads();
    }
    if (t == 0)
        out[0] = (float)(s[0] / NVOX_D);
}

extern "C" void kernel_launch(void* const* d_in, const int* in_sizes, int n_in,
                              void* d_out, int out_size, void* d_ws, size_t ws_size,
                              hipStream_t stream)
{
    const float* u = (const float*)d_in[0];
    float* part = (float*)d_ws;              // 256 floats = 1 KB of scratch

    jac_partial<<<GRID1, TPB, 0, stream>>>(u, part);
    jac_final<<<1, GRID1, 0, stream>>>(part, (float*)d_out);
}

// Round 8
// 42.522 us; speedup vs baseline: 1.0194x; 1.0194x over previous
//
#include <hip/hip_runtime.h>

// Problem geometry (fixed by the reference): u is (B=2, C=3, D=160, H=192, W=160) float32.
#define Dd 160
#define Hh 192
#define Ww 160
#define HW (Hh * Ww)                       // 30720
#define DHW ((size_t)Dd * HW)              // 4,915,200
#define NVOX_D 9830400.0                   // 2 * 160*192*160

#define TH 8                                // h-rows per block
#define TD 10                               // d-planes per block (sliding window)
#define QROW (Ww / 4)                       // 40 float4-quads per row
#define TPB (QROW * TH)                     // 320 threads = 5 waves
#define NHT (Hh / TH)                       // 24
#define NDS (Dd / TD)                       // 16
#define GRID1 (2 * NHT * NDS)               // 768 blocks = exactly 3 per CU
#define NXCD 8
#define CHUNK (GRID1 / NXCD)                // 96 logical blocks per XCD
#define NWAVE (TPB / 64)                    // 5
#define NHALO (2 * QROW * 3)                // 240 halo quads (2 rows x 3 ch)
#define BLK2 256

__device__ __forceinline__ float4 ld4(const float* p) {
    return *reinterpret_cast<const float4*>(p);
}

// w-gradient for a quad given its left/right edge scalars (jnp.gradient semantics)
__device__ __forceinline__ float4 wgrad(float4 cc, float lft, float rgt, int w0) {
    float4 g;
    g.x = (w0 == 0)      ? (cc.y - cc.x) : 0.5f * (cc.y - lft);
    g.y = 0.5f * (cc.z - cc.x);
    g.z = 0.5f * (cc.w - cc.y);
    g.w = (w0 + 4 == Ww) ? (cc.w - cc.z) : 0.5f * (rgt - cc.z);
    return g;
}

// relu(-det(J)) for one voxel given the 9 raw (unscaled) finite-difference grads.
__device__ __forceinline__ float relu_negdet(
    float gd0, float gh0, float gw0,
    float gd1, float gh1, float gw1,
    float gd2, float gh2, float gw2)
{
    const float sx = 79.5f;   // (D-1)/2 -> channel 0
    const float sy = 95.5f;   // (H-1)/2 -> channel 1
    const float sz = 79.5f;   // (W-1)/2 -> channel 2
    float dxx = fmaf(sx, gd0, 1.0f);
    float dxy = sx * gh0;
    float dxz = sx * gw0;
    float dyx = sy * gd1;
    float dyy = fmaf(sy, gh1, 1.0f);
    float dyz = sy * gw1;
    float dzz = fmaf(sz, gw2, 1.0f);
    float dzx = sz * gd2;
    float dzy = sz * gh2;
    float det = dxx * (dyy * dzz - dyz * dzy)
              + dxy * (dyz * dzx - dyx * dzz)
              + dxz * (dyx * dzy - dyy * dzx);
    return fmaxf(-det, 0.0f);
}

// LDS-staged sliding d-march: the current plane (TH+2 rows x 3 ch) lives in LDS,
// double-buffered. Per step each thread issues only its 3 incoming center quads
// (+ 240 threads stage the 2 h-halo rows); ALL h/w-neighbor reuse is ds_read.
// Global VMEM per thread-step: 21 -> ~4 instructions; every datum enters the CU once.
__global__ __launch_bounds__(TPB) void jac_partial(const float* __restrict__ u,
                                                   float* __restrict__ part)
{
    __shared__ float4 buf[2][3][TH + 2][QROW];   // 38400 B -> 3 blocks/CU fits
    __shared__ float sred[NWAVE];

    // bijective XCD-chunked swizzle (768 = 8*96, ds fastest): d-neighbors same XCD
    const int lg  = (blockIdx.x % NXCD) * CHUNK + blockIdx.x / NXCD;
    const int ds  = lg % NDS;
    const int ht  = (lg / NDS) % NHT;
    const int b   = lg / (NDS * NHT);

    const int tid = threadIdx.x;
    const int wq  = tid % QROW;
    const int hh  = tid / QROW;
    const int h   = ht * TH + hh;
    const int w0  = wq * 4;

    // jnp.gradient h-edge handling: halo rows are staged CLAMPED, so LDS rows
    // hh / hh+2 always hold rows hm / hp; only the divisor changes at h=0/191.
    const int hm = (h > 0)      ? h - 1 : 0;
    const int hp = (h < Hh - 1) ? h + 1 : Hh - 1;
    const float hinv = 1.0f / (float)(hp - hm);

    const int d0     = ds * TD;
    const int dir    = (ds & 1) ? -1 : 1;              // boustrophedon
    const int dstart = (dir > 0) ? d0 : d0 + TD - 1;

    // channel base pointers at (b, c, d=0, h, w0)
    const float* pcA = u + (size_t)(b * 3 + 0) * DHW + (size_t)h * Ww + w0;
    const float* pcB = pcA + DHW;
    const float* pcC = pcA + 2 * DHW;

    // halo staging assignment: first 240 threads own (channel, above/below, quad)
    const bool is_halo = (tid < NHALO);
    const int hc   = tid / (2 * QROW);                 // 0..2
    const int hsel = (tid / QROW) % 2;                 // 0: row above, 1: below
    const int hwq  = tid % QROW;
    int hrow = ht * TH + (hsel ? TH : -1);
    hrow = (hrow < 0) ? 0 : ((hrow > Hh - 1) ? Hh - 1 : hrow);
    const int hlrow = hsel ? TH + 1 : 0;
    const float* phal = u + (size_t)(b * 3 + hc) * DHW + (size_t)hrow * Ww + hwq * 4;

    // prologue: register window (x0 = behind plane, x1 = plane dstart) + stage buf[0]
    float4 a0, a1, b0, b1, c0, c1;
    {
        int db = dstart - dir;
        db = (db < 0) ? 0 : ((db > Dd - 1) ? Dd - 1 : db);
        const size_t om = (size_t)db * HW;
        const size_t oc = (size_t)dstart * HW;
        a0 = ld4(pcA + om);  a1 = ld4(pcA + oc);
        b0 = ld4(pcB + om);  b1 = ld4(pcB + oc);
        c0 = ld4(pcC + om);  c1 = ld4(pcC + oc);
        buf[0][0][hh + 1][wq] = a1;
        buf[0][1][hh + 1][wq] = b1;
        buf[0][2][hh + 1][wq] = c1;
        if (is_halo) buf[0][hc][hlrow][hwq] = ld4(phal + oc);
    }
    __syncthreads();

    float acc = 0.0f;

    #pragma unroll 2
    for (int i = 0; i < TD; ++i) {
        const int cur = i & 1;
        const int nxt = cur ^ 1;
        const int d = dstart + dir * i;
        int dn = d + dir;                               // incoming plane
        dn = (dn < 0) ? 0 : ((dn > Dd - 1) ? Dd - 1 : dn);
        const float dinvs = (float)dir * ((d > 0 && d < Dd - 1) ? 0.5f : 1.0f);
        const size_t odn = (size_t)dn * HW;
        const bool do_stage = (i < TD - 1);

        // issue incoming-plane global loads first (latency hides under compute)
        float4 a2 = ld4(pcA + odn);
        float4 b2 = ld4(pcB + odn);
        float4 c2 = ld4(pcC + odn);
        float4 hal = make_float4(0.f, 0.f, 0.f, 0.f);
        if (do_stage && is_halo) hal = ld4(phal + odn);

        // h-neighbor quads at plane d from LDS (2-way bank aliasing = free)
        float4 rAm = buf[cur][0][hh][wq],     rAp = buf[cur][0][hh + 2][wq];
        float4 rBm = buf[cur][1][hh][wq],     rBp = buf[cur][1][hh + 2][wq];
        float4 rCm = buf[cur][2][hh][wq],     rCp = buf[cur][2][hh + 2][wq];

        // w-edge scalars at plane d from LDS (center row)
        const int wqm = (wq > 0) ? wq - 1 : 0;                 // clamped; unused at edge
        const int wqp = (wq < QROW - 1) ? wq + 1 : QROW - 1;
        float lA = buf[cur][0][hh + 1][wqm].w, rA = buf[cur][0][hh + 1][wqp].x;
        float lB = buf[cur][1][hh + 1][wqm].w, rB = buf[cur][1][hh + 1][wqp].x;
        float lC = buf[cur][2][hh + 1][wqm].w, rC = buf[cur][2][hh + 1][wqp].x;

        // gradients (raw, unscaled)
        float4 gwA = wgrad(a1, lA, rA, w0);
        float4 gwB = wgrad(b1, lB, rB, w0);
        float4 gwC = wgrad(c1, lC, rC, w0);

        float4 ghA = make_float4((rAp.x - rAm.x) * hinv, (rAp.y - rAm.y) * hinv,
                                 (rAp.z - rAm.z) * hinv, (rAp.w - rAm.w) * hinv);
        float4 ghB = make_float4((rBp.x - rBm.x) * hinv, (rBp.y - rBm.y) * hinv,
                                 (rBp.z - rBm.z) * hinv, (rBp.w - rBm.w) * hinv);
        float4 ghC = make_float4((rCp.x - rCm.x) * hinv, (rCp.y - rCm.y) * hinv,
                                 (rCp.z - rCm.z) * hinv, (rCp.w - rCm.w) * hinv);

        float4 gdA = make_float4((a2.x - a0.x) * dinvs, (a2.y - a0.y) * dinvs,
                                 (a2.z - a0.z) * dinvs, (a2.w - a0.w) * dinvs);
        float4 gdB = make_float4((b2.x - b0.x) * dinvs, (b2.y - b0.y) * dinvs,
                                 (b2.z - b0.z) * dinvs, (b2.w - b0.w) * dinvs);
        float4 gdC = make_float4((c2.x - c0.x) * dinvs, (c2.y - c0.y) * dinvs,
                                 (c2.z - c0.z) * dinvs, (c2.w - c0.w) * dinvs);

        acc += relu_negdet(gdA.x, ghA.x, gwA.x, gdB.x, ghB.x, gwB.x, gdC.x, ghC.x, gwC.x)
             + relu_negdet(gdA.y, ghA.y, gwA.y, gdB.y, ghB.y, gwB.y, gdC.y, ghC.y, gwC.y)
             + relu_negdet(gdA.z, ghA.z, gwA.z, gdB.z, ghB.z, gwB.z, gdC.z, ghC.z, gwC.z)
             + relu_negdet(gdA.w, ghA.w, gwA.w, gdB.w, ghB.w, gwB.w, gdC.w, ghC.w, gwC.w);

        // stage incoming plane into the other buffer; single barrier per step
        // (step i reads buf[cur], writes buf[nxt]; barrier separates step i's
        //  reads of buf[cur] from step i+1's writes to it, and step i's writes
        //  to buf[nxt] from step i+1's reads of it)
        if (do_stage) {
            buf[nxt][0][hh + 1][wq] = a2;
            buf[nxt][1][hh + 1][wq] = b2;
            buf[nxt][2][hh + 1][wq] = c2;
            if (is_halo) buf[nxt][hc][hlrow][hwq] = hal;
            __syncthreads();
        }

        // slide the window
        a0 = a1; a1 = a2;
        b0 = b1; b1 = b2;
        c0 = c1; c1 = c2;
    }

    // deterministic block reduction: wave64 shuffle tree, then 5-word LDS
    #pragma unroll
    for (int off = 32; off > 0; off >>= 1)
        acc += __shfl_down(acc, off, 64);
    const int lane = tid & 63;
    const int wid  = tid >> 6;
    if (lane == 0) sred[wid] = acc;
    __syncthreads();
    if (tid == 0)
        part[lg] = ((sred[0] + sred[1]) + (sred[2] + sred[3])) + sred[4];
}

// 768 partials -> mean. 3 independent loads per thread, f64 fixed-tree reduce
// (deterministic; f64 kills the ~2e8-magnitude sum's rounding concern).
__global__ __launch_bounds__(BLK2) void jac_final(const float* __restrict__ part,
                                                  float* __restrict__ out)
{
    const int t = threadIdx.x;
    double a = (double)part[t] + (double)part[t + 256] + (double)part[t + 512];
    __shared__ double s[BLK2];
    s[t] = a;
    __syncthreads();
    #pragma unroll
    for (int off = BLK2 / 2; off > 0; off >>= 1) {
        if (t < off) s[t] += s[t + off];
        __syncthreads();
    }
    if (t == 0)
        out[0] = (float)(s[0] / NVOX_D);
}

extern "C" void kernel_launch(void* const* d_in, const int* in_sizes, int n_in,
                              void* d_out, int out_size, void* d_ws, size_t ws_size,
                              hipStream_t stream)
{
    const float* u = (const float*)d_in[0];
    float* part = (float*)d_ws;              // 768 floats = 3 KB of scratch

    jac_partial<<<GRID1, TPB, 0, stream>>>(u, part);
    jac_final<<<1, BLK2, 0, stream>>>(part, (float*)d_out);
}